// Round 4
// baseline (706.851 us; speedup 1.0000x reference)
//
#include <hip/hip_runtime.h>

#define BB 16
#define CC 64
#define NN 65536
#define NBV 4
// primary (transposed) path: 256 blocks/batch x 4 waves
#define PNP 1024
#define PBP (BB * PNP)
// fallback (c-major, round-3 proven) path
#define FNP 512
#define FBP (BB * FNP)

// ws layout primary (fp32 elems):
//   score B*N | bval 2*PBP | bidx 2*PBP (int) | wpart B*256*64 | sspart PBP | x_t B*N*64
// x_t[b][n][c]: each pixel's 64 channels contiguous (256 B) -> k_iter_t waves read pure
// sequential 16 KB runs (the pattern the 6.3 TB/s copy ubench uses), vs the c-major
// 256KB-stride multi-stream pattern measured at ~2.2-2.5 TB/s in rounds 0-3.

// ---------- primary path ----------

// x [b][c][n] -> x_t [b][n][c]. Tile: 256 pixels x 32 channels via LDS.
// Reads: 32 rows x 1KB contiguous chunks. Writes: 128B-aligned half-rows (full lines).
__global__ __launch_bounds__(256)
void k_transpose(const float* __restrict__ x, float* __restrict__ xt) {
    int tile = blockIdx.x, h = blockIdx.y, b = blockIdx.z;
    int t = threadIdx.x;
    int c = t & 31, oct = t >> 5;
    __shared__ float lds[256][36];   // +4 pad: b128-aligned rows, ~2-way write banks
    const float* src = x + ((size_t)(b * 64 + h * 32 + c)) * NN + tile * 256 + oct * 32;
    float4 v[8];
    #pragma unroll
    for (int j = 0; j < 8; j++) v[j] = ((const float4*)src)[j];
    #pragma unroll
    for (int j = 0; j < 8; j++) {
        lds[oct * 32 + j * 4 + 0][c] = v[j].x;
        lds[oct * 32 + j * 4 + 1][c] = v[j].y;
        lds[oct * 32 + j * 4 + 2][c] = v[j].z;
        lds[oct * 32 + j * 4 + 3][c] = v[j].w;
    }
    __syncthreads();
    float* dst = xt + ((size_t)b * NN + tile * 256 + t) * 64 + h * 32;
    #pragma unroll
    for (int k = 0; k < 8; k++) ((float4*)dst)[k] = *(const float4*)&lds[t][k * 4];
}

// Initial argmax over score_init + zero selectedPos. 256 blocks/batch, 1 px/thread.
// Tie rule everywhere: larger value wins; equal -> smaller index (np.argmax = first max).
__global__ __launch_bounds__(256)
void k_argmax1(const float* __restrict__ sc_in,
               float* __restrict__ bval, int* __restrict__ bidx,
               float* __restrict__ sel_out) {
    int b = blockIdx.y, blk = blockIdx.x, tid = threadIdx.x;
    int lane = tid & 63, wv = tid >> 6;
    int n0 = blk * 256 + tid;
    float v = sc_in[(size_t)b * NN + n0]; int vi = n0;
    sel_out[(size_t)b * NN + n0] = 0.f;
    #pragma unroll
    for (int off = 32; off >= 1; off >>= 1) {
        float ov = __shfl_down(v, off, 64); int oi = __shfl_down(vi, off, 64);
        if (ov > v || (ov == v && oi < vi)) { v = ov; vi = oi; }
    }
    if (lane == 0) { bval[b * PNP + blk * 4 + wv] = v; bidx[b * PNP + blk * 4 + wv] = vi; }
}

// Transposed-layout iteration. grid=(256,B), 256 thr, 1 pixel/thread.
// Lane reads its pixel's 64 channels = 256B contiguous (16 dwordx4); wave = 16KB seq.
// d2 lane-local vs LDS-broadcast raw; acc reduced via LDS transpose-tree (2 c-halves).
// ~100 VGPR + 37KB LDS -> ~16 waves/CU (2x round-3), hedging the latency-cap theory.
__global__ __launch_bounds__(256, 2)
void k_iter_t(const float* __restrict__ xt, const float* __restrict__ score_in,
              float* __restrict__ score_out,
              float* __restrict__ bval, int* __restrict__ bidx,
              float* __restrict__ wpart, float* __restrict__ sspart,
              float* __restrict__ sim_out, int iter) {
    int b = blockIdx.y, blk = blockIdx.x, tid = threadIdx.x;
    int lane = tid & 63, wv = tid >> 6;
    __shared__ float sv[256]; __shared__ int si[256];
    __shared__ float raw_s[64];
    __shared__ float lacc[256][33];   // 33: 2-way banks on row writes & column reads
    __shared__ float lq[8][32];

    int rb = (iter & 1) * PBP, wb = ((iter & 1) ^ 1) * PBP;

    {   // stage-2 argmax over PNP=1024 partials (pixel-ordered -> tie-break on stored idx ok)
        const float* bv = bval + rb + b * PNP;
        const int* bi = bidx + rb + b * PNP;
        float v = bv[tid]; int vi = bi[tid];
        #pragma unroll
        for (int s = 1; s < 4; s++) {
            float ov = bv[tid + 256 * s]; int oi = bi[tid + 256 * s];
            if (ov > v || (ov == v && oi < vi)) { v = ov; vi = oi; }
        }
        sv[tid] = v; si[tid] = vi;
        __syncthreads();
        for (int st = 128; st > 0; st >>= 1) {
            if (tid < st) {
                float ov = sv[tid + st]; int oi = si[tid + st];
                if (ov > sv[tid] || (ov == sv[tid] && oi < si[tid])) { sv[tid] = ov; si[tid] = oi; }
            }
            __syncthreads();
        }
    }
    int ind = si[0];
    if (tid < 64) raw_s[tid] = xt[((size_t)b * NN + ind) * 64 + tid];  // one 256B coalesced read
    __syncthreads();

    int n0 = blk * 256 + tid;
    const float4* xp = (const float4*)(xt + ((size_t)b * NN + n0) * 64);
    float4 xa[16];
    #pragma unroll
    for (int j = 0; j < 16; j++) xa[j] = xp[j];

    float d2 = 0.f;
    #pragma unroll
    for (int j = 0; j < 16; j++) {
        float4 r4 = *(const float4*)&raw_s[j * 4];   // LDS broadcast, short live range
        float dx = xa[j].x - r4.x, dy = xa[j].y - r4.y;
        float dz = xa[j].z - r4.z, dw = xa[j].w - r4.w;
        d2 = fmaf(dx, dx, d2); d2 = fmaf(dy, dy, d2);
        d2 = fmaf(dz, dz, d2); d2 = fmaf(dw, dw, d2);
    }
    float sim = expf(-sqrtf(fmaxf(d2, 1e-12f)) * 0.05f);

    const size_t sb = (size_t)b * NN;
    sim_out[((size_t)(b * NBV + iter)) * NN + n0] = sim;
    const bool upd = (iter < 3);
    float ss = sim, smax = -1e30f; int smaxi = n0;
    if (upd) {
        float nc = score_in[sb + n0] * (1.f - sim);
        score_out[sb + n0] = nc;
        smax = nc;
    }

    // acc: Sum_n sim_n * x_t[n][c] via LDS transpose-tree, two 32-channel halves
    #pragma unroll
    for (int h = 0; h < 2; h++) {
        #pragma unroll
        for (int j = 0; j < 8; j++) {
            float4 xv4 = xa[h * 8 + j];
            lacc[tid][j * 4 + 0] = sim * xv4.x;
            lacc[tid][j * 4 + 1] = sim * xv4.y;
            lacc[tid][j * 4 + 2] = sim * xv4.z;
            lacc[tid][j * 4 + 3] = sim * xv4.w;
        }
        __syncthreads();
        int c = tid & 31, oct = tid >> 5;
        float s = 0.f;
        #pragma unroll
        for (int r = 0; r < 32; r++) s += lacc[oct * 32 + r][c];
        lq[oct][c] = s;
        __syncthreads();
        if (tid < 32) {
            float t4 = 0.f;
            #pragma unroll
            for (int o = 0; o < 8; o++) t4 += lq[o][tid];
            wpart[((size_t)b * 256 + blk) * 64 + h * 32 + tid] = t4;
        }
        __syncthreads();   // protect lacc/lq reuse across halves
    }

    // wave reductions: sim-sum + fused stage-1 argmax of the NEW score
    #pragma unroll
    for (int off = 32; off >= 1; off >>= 1) ss += __shfl_down(ss, off, 64);
    if (lane == 0) sspart[b * PNP + blk * 4 + wv] = ss;
    if (upd) {
        float v = smax; int idx = smaxi;
        #pragma unroll
        for (int off = 32; off >= 1; off >>= 1) {
            float ov = __shfl_down(v, off, 64); int oi = __shfl_down(idx, off, 64);
            if (ov > v || (ov == v && oi < idx)) { v = ov; idx = oi; }
        }
        if (lane == 0) { bval[wb + b * PNP + blk * 4 + wv] = v; bidx[wb + b * PNP + blk * 4 + wv] = idx; }
    }
}

__global__ __launch_bounds__(256)
void k_fin(const float* __restrict__ wpart, const float* __restrict__ sspart,
           float* __restrict__ vec_out, int iter) {
    int b = blockIdx.x, tid = threadIdx.x;
    int c = tid & 63, q = tid >> 6;
    __shared__ float lw[4][64];
    __shared__ float lss[256];
    float s4 = 0.f;
    #pragma unroll
    for (int i = 0; i < 4; i++) s4 += sspart[b * PNP + i * 256 + tid];
    lss[tid] = s4;
    float w = 0.f;
    for (int i = 0; i < 64; i++) w += wpart[((size_t)b * 256 + q * 64 + i) * 64 + c];
    lw[q][c] = w;
    __syncthreads();
    for (int st = 128; st > 0; st >>= 1) {
        if (tid < st) lss[tid] += lss[tid + st];
        __syncthreads();
    }
    if (tid < 64) {
        float tot = (lw[0][tid] + lw[1][tid]) + (lw[2][tid] + lw[3][tid]);
        vec_out[(b * NBV + iter) * 64 + tid] = tot / lss[0];
    }
}

// ---------- fallback path (round-3 proven, used only if ws too small) ----------

__global__ __launch_bounds__(256)
void k_argmax1_fb(const float* __restrict__ sc_in,
                  float* __restrict__ bval, int* __restrict__ bidx,
                  float* __restrict__ sel_out) {
    int b = blockIdx.y, blk = blockIdx.x, tid = threadIdx.x;
    int lane = tid & 63, wv = tid >> 6;
    int n0 = blk * 512 + tid * 2;
    const float* s = sc_in + (size_t)b * NN;
    float v0 = s[n0], v1 = s[n0 + 1];
    float v = v0; int vi = n0;
    if (v1 > v) { v = v1; vi = n0 + 1; }
    sel_out[(size_t)b * NN + n0] = 0.f;
    sel_out[(size_t)b * NN + n0 + 1] = 0.f;
    #pragma unroll
    for (int off = 32; off >= 1; off >>= 1) {
        float ov = __shfl_down(v, off, 64); int oi = __shfl_down(vi, off, 64);
        if (ov > v || (ov == v && oi < vi)) { v = ov; vi = oi; }
    }
    if (lane == 0) { bval[b * FNP + blk * 4 + wv] = v; bidx[b * FNP + blk * 4 + wv] = vi; }
}

__global__ __launch_bounds__(256, 2)
void k_iter_fb(const float* __restrict__ x, const float* __restrict__ score_in,
               float* __restrict__ score_out,
               float* __restrict__ bval, int* __restrict__ bidx,
               float* __restrict__ wpart, float* __restrict__ sspart,
               float* __restrict__ sim_out, int iter) {
    int b = blockIdx.y, blk = blockIdx.x, tid = threadIdx.x;
    int lane = tid & 63, wv = tid >> 6;
    __shared__ float sv[256]; __shared__ int si[256];
    __shared__ float raw_s[64];
    int rb = (iter & 1) * FBP, wb = ((iter & 1) ^ 1) * FBP;
    {
        const float* bv = bval + rb + b * FNP;
        const int* bi = bidx + rb + b * FNP;
        float v = bv[tid]; int vi = bi[tid];
        float v2 = bv[tid + 256]; int vi2 = bi[tid + 256];
        if (v2 > v || (v2 == v && vi2 < vi)) { v = v2; vi = vi2; }
        sv[tid] = v; si[tid] = vi;
        __syncthreads();
        for (int st = 128; st > 0; st >>= 1) {
            if (tid < st) {
                float ov = sv[tid + st]; int oi = si[tid + st];
                if (ov > sv[tid] || (ov == sv[tid] && oi < si[tid])) { sv[tid] = ov; si[tid] = oi; }
            }
            __syncthreads();
        }
    }
    int ind = si[0];
    if (tid < 64) raw_s[tid] = x[((size_t)(b * 64 + tid)) * NN + ind];
    __syncthreads();
    int p = blk * 4 + wv;
    int n0 = blk * 512 + wv * 128 + lane * 2;
    const float* xb = x + (size_t)b * 64 * NN + n0;
    const size_t sb = (size_t)b * NN;
    const bool upd = (iter < 3);
    float2 sc = make_float2(0.f, 0.f);
    if (upd) sc = *(const float2*)(score_in + sb + n0);
    float2 xv[64];
    #pragma unroll
    for (int c = 0; c < 64; c++) xv[c] = *(const float2*)(xb + (size_t)c * NN);
    float d2x = 0.f, d2y = 0.f;
    #pragma unroll
    for (int c = 0; c < 64; c++) {
        float r = raw_s[c];
        float dx = xv[c].x - r, dy = xv[c].y - r;
        d2x = fmaf(dx, dx, d2x); d2y = fmaf(dy, dy, d2y);
    }
    float simx = expf(-sqrtf(fmaxf(d2x, 1e-12f)) * 0.05f);
    float simy = expf(-sqrtf(fmaxf(d2y, 1e-12f)) * 0.05f);
    *(float2*)(sim_out + ((size_t)(b * NBV + iter)) * NN + n0) = make_float2(simx, simy);
    float ss = simx + simy;
    float smax = -1e30f; int smaxi = 0x7fffffff;
    if (upd) {
        float ncx = sc.x * (1.f - simx), ncy = sc.y * (1.f - simy);
        *(float2*)(score_out + sb + n0) = make_float2(ncx, ncy);
        smax = ncx; smaxi = n0;
        if (ncy > smax) { smax = ncy; smaxi = n0 + 1; }
    }
    float accl[64];
    #pragma unroll
    for (int c = 0; c < 64; c++) accl[c] = fmaf(simx, xv[c].x, simy * xv[c].y);
    #pragma unroll
    for (int c = 0; c < 64; c++) {
        float v = accl[c];
        #pragma unroll
        for (int off = 32; off >= 1; off >>= 1) v += __shfl_down(v, off, 64);
        if (lane == 0) wpart[((size_t)b * FNP + p) * 64 + c] = v;
    }
    #pragma unroll
    for (int off = 32; off >= 1; off >>= 1) ss += __shfl_down(ss, off, 64);
    if (lane == 0) sspart[b * FNP + p] = ss;
    if (upd) {
        #pragma unroll
        for (int off = 32; off >= 1; off >>= 1) {
            float ov = __shfl_down(smax, off, 64); int oi = __shfl_down(smaxi, off, 64);
            if (ov > smax || (ov == smax && oi < smaxi)) { smax = ov; smaxi = oi; }
        }
        if (lane == 0) { bval[wb + b * FNP + p] = smax; bidx[wb + b * FNP + p] = smaxi; }
    }
}

__global__ __launch_bounds__(256)
void k_fin_fb(const float* __restrict__ wpart, const float* __restrict__ sspart,
              float* __restrict__ vec_out, int iter) {
    int b = blockIdx.x, tid = threadIdx.x;
    int c = tid & 63, q = tid >> 6;
    __shared__ float lw[4][64];
    __shared__ float lss[256];
    lss[tid] = sspart[b * FNP + 2 * tid] + sspart[b * FNP + 2 * tid + 1];
    float w = 0.f;
    for (int i = 0; i < 128; i++) w += wpart[((size_t)b * FNP + q * 128 + i) * 64 + c];
    lw[q][c] = w;
    __syncthreads();
    for (int st = 128; st > 0; st >>= 1) {
        if (tid < st) lss[tid] += lss[tid + st];
        __syncthreads();
    }
    if (tid < 64) {
        float tot = (lw[0][tid] + lw[1][tid]) + (lw[2][tid] + lw[3][tid]);
        vec_out[(b * NBV + iter) * 64 + tid] = tot / lss[0];
    }
}

extern "C" void kernel_launch(void* const* d_in, const int* in_sizes, int n_in,
                              void* d_out, int out_size, void* d_ws, size_t ws_size,
                              hipStream_t stream) {
    const float* x = (const float*)d_in[0];           // [B,C,H,W] fp32
    const float* sc_in = (const float*)d_in[1];       // [B,N] fp32
    float* out = (float*)d_out;
    float* vec_out = out;                             // B*4*C
    float* sim_out = vec_out + (size_t)BB * NBV * CC; // B*4*N
    float* sel_out = sim_out + (size_t)BB * NBV * NN; // B*N

    float* ws = (float*)d_ws;
    float* score = ws;                                // B*N

    // primary layout
    float* bval = ws + (size_t)BB * NN;               // 2*PBP
    int* bidx = (int*)(bval + 2 * PBP);               // 2*PBP
    float* wpart = bval + 4 * PBP;                    // B*256*64
    float* sspart = wpart + (size_t)BB * 256 * 64;    // PBP
    float* xt = sspart + PBP;                         // B*N*64 (16B-aligned)
    size_t need = ((size_t)BB * NN + 4 * PBP + (size_t)BB * 256 * 64 + PBP
                   + (size_t)BB * NN * 64) * sizeof(float);   // ~274 MB

    if (ws_size >= need) {
        k_transpose<<<dim3(256, 2, BB), 256, 0, stream>>>(x, xt);
        k_argmax1<<<dim3(256, BB), 256, 0, stream>>>(sc_in, bval, bidx, sel_out);
        for (int it = 0; it < NBV; it++) {
            const float* s_in = (it == 0) ? sc_in : score;
            k_iter_t<<<dim3(256, BB), 256, 0, stream>>>(xt, s_in, score, bval, bidx,
                                                        wpart, sspart, sim_out, it);
            k_fin<<<dim3(BB), 256, 0, stream>>>(wpart, sspart, vec_out, it);
        }
    } else {
        // fallback: round-3 proven c-major path
        float* fbval = ws + (size_t)BB * NN;          // 2*FBP
        int* fbidx = (int*)(fbval + 2 * FBP);         // 2*FBP
        float* fwpart = fbval + 4 * FBP;              // FBP*64
        float* fsspart = fwpart + (size_t)FBP * 64;   // FBP
        k_argmax1_fb<<<dim3(128, BB), 256, 0, stream>>>(sc_in, fbval, fbidx, sel_out);
        for (int it = 0; it < NBV; it++) {
            const float* s_in = (it == 0) ? sc_in : score;
            k_iter_fb<<<dim3(128, BB), 256, 0, stream>>>(x, s_in, score, fbval, fbidx,
                                                         fwpart, fsspart, sim_out, it);
            k_fin_fb<<<dim3(BB), 256, 0, stream>>>(fwpart, fsspart, vec_out, it);
        }
    }
}